// Round 1
// baseline (249.402 us; speedup 1.0000x reference)
//
#include <hip/hip_runtime.h>
#include <hip/hip_bf16.h>
#include <math.h>

#define N 4096
#define D 1024
#define NINST 8
#define NGROUP (N / NINST)
#define ALPHA 20.0f
#define MARGIN 0.5f

typedef __attribute__((ext_vector_type(8))) short bf16x8;
typedef __attribute__((ext_vector_type(4))) float f32x4;

__device__ __forceinline__ unsigned fkey(float f) {
    int b = __float_as_int(f);
    return (b >= 0) ? ((unsigned)b | 0x80000000u) : ~(unsigned)b;
}
__device__ __forceinline__ float fdec(unsigned u) {
    int b = (u & 0x80000000u) ? (int)(u ^ 0x80000000u) : ~(int)u;
    return __int_as_float(b);
}

// ---------------- K1: row L2-normalize, fp32 -> bf16 + inv_norm ----------------
__global__ __launch_bounds__(256) void k_norm(const float* __restrict__ in,
                                              ushort* __restrict__ xn,
                                              float* __restrict__ inv_norm) {
    int row = blockIdx.x;
    int t = threadIdx.x;
    const float4* p = (const float4*)(in + (size_t)row * D);
    float4 v = p[t];                       // 256 threads * 4 = 1024
    float ss = v.x * v.x + v.y * v.y + v.z * v.z + v.w * v.w;
    int lane = t & 63, wid = t >> 6;
    #pragma unroll
    for (int off = 1; off < 64; off <<= 1) ss += __shfl_xor(ss, off);
    __shared__ float sred[4];
    if (lane == 0) sred[wid] = ss;
    __syncthreads();
    float tot = sred[0] + sred[1] + sred[2] + sred[3];
    float inv = 1.0f / sqrtf(tot);
    if (t == 0) inv_norm[row] = inv;
    ushort4 o;
    __hip_bfloat16 h;
    h = __float2bfloat16(v.x * inv); o.x = *(ushort*)&h;
    h = __float2bfloat16(v.y * inv); o.y = *(ushort*)&h;
    h = __float2bfloat16(v.z * inv); o.z = *(ushort*)&h;
    h = __float2bfloat16(v.w * inv); o.w = *(ushort*)&h;
    ((ushort4*)(xn + (size_t)row * D))[t] = o;
}

// ---------------- K2: exact fp32 positive sims per group (8x8 Gram) ----------------
__global__ __launch_bounds__(64) void k_pos(const float* __restrict__ in,
                                            const float* __restrict__ inv_norm,
                                            float* __restrict__ pos_sims,
                                            float* __restrict__ min_pos) {
    int g = blockIdx.x;
    int t = threadIdx.x;     // 0..63
    int a = t >> 3, b = t & 7;
    int ra = g * 8 + a, rb = g * 8 + b;
    const float4* pa = (const float4*)(in + (size_t)ra * D);
    const float4* pb = (const float4*)(in + (size_t)rb * D);
    float s = 0.f;
    #pragma unroll 4
    for (int i = 0; i < D / 4; ++i) {
        float4 x = pa[i], y = pb[i];
        s += x.x * y.x + x.y * y.y + x.z * y.z + x.w * y.w;
    }
    float sim = s * inv_norm[ra] * inv_norm[rb];
    __shared__ float sg[8][8];
    sg[a][b] = sim;
    __syncthreads();
    if (t < 8) {
        float mn = 1e30f;
        int idx = 0;
        #pragma unroll
        for (int b2 = 0; b2 < 8; ++b2) {
            if (b2 == t) continue;
            float v = sg[t][b2];
            mn = fminf(mn, v);
            pos_sims[(size_t)(g * 8 + t) * 8 + idx] = v;
            ++idx;
        }
        min_pos[g * 8 + t] = mn;
    }
}

// ---------------- K3: bf16 MFMA sim tiles + fused negative-side reductions ----------------
// grid (32, 32); block 256 = 4 waves in 2x2; 128x128 tile per block.
__global__ __launch_bounds__(256) void k_neg(const ushort* __restrict__ xn,
                                             const float* __restrict__ min_pos,
                                             float* __restrict__ sum_part,
                                             int* __restrict__ cnt_part,
                                             float* __restrict__ max_part,
                                             unsigned* __restrict__ gmax) {
    int rt = blockIdx.y, ct = blockIdx.x;
    int R0 = rt * 128, C0 = ct * 128;
    int t = threadIdx.x, lane = t & 63, wid = t >> 6;
    int wr = wid >> 1, wc = wid & 1;

    __shared__ float sMin[128];
    if (t < 128) sMin[t] = min_pos[R0 + t];
    __syncthreads();

    int rbase = R0 + wr * 64;
    int cbase = C0 + wc * 64;
    int lrow = lane & 15;
    int kgrp = lane >> 4;    // 0..3 -> k-octet

    f32x4 zero = {0.f, 0.f, 0.f, 0.f};
    f32x4 acc[4][4];
    #pragma unroll
    for (int m = 0; m < 4; ++m)
        #pragma unroll
        for (int n = 0; n < 4; ++n) acc[m][n] = zero;

    const ushort* pA = xn + (size_t)(rbase + lrow) * D + kgrp * 8;
    const ushort* pB = xn + (size_t)(cbase + lrow) * D + kgrp * 8;

    for (int k0 = 0; k0 < D; k0 += 32) {
        bf16x8 a[4], b[4];
        #pragma unroll
        for (int m = 0; m < 4; ++m)
            a[m] = *(const bf16x8*)(pA + (size_t)m * 16 * D + k0);
        #pragma unroll
        for (int n = 0; n < 4; ++n)
            b[n] = *(const bf16x8*)(pB + (size_t)n * 16 * D + k0);
        #pragma unroll
        for (int m = 0; m < 4; ++m)
            #pragma unroll
            for (int n = 0; n < 4; ++n)
                acc[m][n] = __builtin_amdgcn_mfma_f32_16x16x32_bf16(a[m], b[n], acc[m][n], 0, 0, 0);
    }

    // epilogue: per-row negative stats + global max
    float allmax = -1e30f;
    int pc = ct * 2 + wc;
    #pragma unroll
    for (int m = 0; m < 4; ++m) {
        #pragma unroll
        for (int reg = 0; reg < 4; ++reg) {
            int lr = wr * 64 + m * 16 + kgrp * 4 + reg;   // local row in [0,128)
            int grow = R0 + lr;
            float th = sMin[lr] - 0.05f;
            int gi = grow >> 3;
            float rs = 0.f, rm = -1e30f;
            int rc = 0;
            #pragma unroll
            for (int n = 0; n < 4; ++n) {
                int gcol = cbase + n * 16 + lrow;
                float s = acc[m][n][reg];
                allmax = fmaxf(allmax, s);
                if ((gcol >> 3) != gi) {
                    rm = fmaxf(rm, s);
                    if (s > th) { rs += log1pf(expf(ALPHA * (s - MARGIN))); rc += 1; }
                }
            }
            // reduce across the 16 col-lanes (same kgrp group)
            #pragma unroll
            for (int off = 1; off < 16; off <<= 1) {
                rs += __shfl_xor(rs, off);
                rc += __shfl_xor(rc, off);
                rm = fmaxf(rm, __shfl_xor(rm, off));
            }
            if (lrow == 0) {
                sum_part[(size_t)pc * N + grow] = rs;
                cnt_part[(size_t)pc * N + grow] = rc;
                max_part[(size_t)pc * N + grow] = rm;
            }
        }
    }
    #pragma unroll
    for (int off = 1; off < 64; off <<= 1) allmax = fmaxf(allmax, __shfl_xor(allmax, off));
    if (lane == 0) atomicMax(gmax, fkey(allmax));
}

// ---------------- K4a: per-row combine ----------------
__global__ __launch_bounds__(256) void k_row(const float* __restrict__ sum_part,
                                             const int* __restrict__ cnt_part,
                                             const float* __restrict__ max_part,
                                             const float* __restrict__ pos_sims,
                                             const float* __restrict__ min_pos,
                                             const unsigned* __restrict__ gmax,
                                             float* __restrict__ row_loss) {
    int row = blockIdx.x * 256 + threadIdx.x;
    if (row >= N) return;
    float base = fmaxf(fdec(*gmax) - 0.1f, MARGIN + 0.2f);
    float ns = 0.f, nm = -1e30f;
    int nc = 0;
    for (int p = 0; p < 64; ++p) {
        ns += sum_part[(size_t)p * N + row];
        nc += cnt_part[(size_t)p * N + row];
        nm = fmaxf(nm, max_part[(size_t)p * N + row]);
    }
    float neg_loss = (nc > 0) ? ns / (float)nc : log1pf(expf(ALPHA * (nm - MARGIN)));
    float ps = 0.f;
    int pcnt = 0;
    float mn = min_pos[row];
    #pragma unroll
    for (int i = 0; i < NINST - 1; ++i) {
        float s = pos_sims[(size_t)row * 8 + i];
        if (s < base) { ps += log1pf(expf(-2.0f * (s - MARGIN))); pcnt++; }
    }
    float pos_loss = (pcnt > 0) ? ps / (float)pcnt : log1pf(expf(-2.0f * (mn - MARGIN)));
    row_loss[row] = pos_loss + neg_loss;
}

// ---------------- K4b: deterministic mean ----------------
__global__ __launch_bounds__(256) void k_final(const float* __restrict__ row_loss,
                                               float* __restrict__ out) {
    __shared__ float sred[256];
    int t = threadIdx.x;
    float s = 0.f;
    for (int i = t; i < N; i += 256) s += row_loss[i];
    sred[t] = s;
    __syncthreads();
    for (int off = 128; off; off >>= 1) {
        if (t < off) sred[t] += sred[t + off];
        __syncthreads();
    }
    if (t == 0) out[0] = sred[0] / (float)N;
}

extern "C" void kernel_launch(void* const* d_in, const int* in_sizes, int n_in,
                              void* d_out, int out_size, void* d_ws, size_t ws_size,
                              hipStream_t stream) {
    const float* in = (const float*)d_in[0];
    float* out = (float*)d_out;

    char* ws = (char*)d_ws;
    ushort*  xn       = (ushort*)(ws);                          // 8 MB
    float*   inv_norm = (float*)(ws + 8388608);                 // 16 KB
    float*   min_pos  = (float*)(ws + 8388608 + 16384);         // 16 KB
    float*   pos_sims = (float*)(ws + 8388608 + 32768);         // 128 KB
    float*   sum_part = (float*)(ws + 8388608 + 32768 + 131072);            // 1 MB
    float*   max_part = (float*)(ws + 8388608 + 32768 + 131072 + 1048576);  // 1 MB
    int*     cnt_part = (int*)  (ws + 8388608 + 32768 + 131072 + 2097152);  // 1 MB
    float*   row_loss = (float*)(ws + 8388608 + 32768 + 131072 + 3145728);  // 16 KB
    unsigned* gmax    = (unsigned*)(ws + 8388608 + 32768 + 131072 + 3145728 + 16384);

    hipMemsetAsync(gmax, 0, sizeof(unsigned), stream);

    k_norm<<<N, 256, 0, stream>>>(in, xn, inv_norm);
    k_pos<<<NGROUP, 64, 0, stream>>>(in, inv_norm, pos_sims, min_pos);
    k_neg<<<dim3(32, 32), 256, 0, stream>>>(xn, min_pos, sum_part, cnt_part, max_part, gmax);
    k_row<<<N / 256, 256, 0, stream>>>(sum_part, cnt_part, max_part, pos_sims, min_pos, gmax, row_loss);
    k_final<<<1, 256, 0, stream>>>(row_loss, out);
}

// Round 2
// 157.316 us; speedup vs baseline: 1.5854x; 1.5854x over previous
//
#include <hip/hip_runtime.h>
#include <hip/hip_bf16.h>
#include <math.h>

#define N 4096
#define D 1024
#define NINST 8
#define NGROUP (N / NINST)
#define ALPHA 20.0f
#define MARGIN 0.5f

typedef __attribute__((ext_vector_type(8))) short bf16x8;
typedef __attribute__((ext_vector_type(4))) float f32x4;

__device__ __forceinline__ unsigned fkey(float f) {
    int b = __float_as_int(f);
    return (b >= 0) ? ((unsigned)b | 0x80000000u) : ~(unsigned)b;
}
__device__ __forceinline__ float fdec(unsigned u) {
    int b = (u & 0x80000000u) ? (int)(u ^ 0x80000000u) : ~(int)u;
    return __int_as_float(b);
}

// stable fast softplus: log1p(exp(x)) = max(x,0) + log(1 + exp(-|x|))
__device__ __forceinline__ float softplus(float x) {
    float z = __expf(-fabsf(x));
    return fmaxf(x, 0.0f) + __logf(1.0f + z);
}

// async global -> LDS, 16 bytes per lane (lds dest: wave-uniform base + lane*16)
__device__ __forceinline__ void gld16(const void* g, void* l) {
    __builtin_amdgcn_global_load_lds(
        (const __attribute__((address_space(1))) void*)g,
        (__attribute__((address_space(3))) void*)l, 16, 0, 0);
}

// ---------------- K1: row L2-normalize, fp32 -> bf16 + inv_norm ----------------
__global__ __launch_bounds__(256) void k_norm(const float* __restrict__ in,
                                              ushort* __restrict__ xn,
                                              float* __restrict__ inv_norm) {
    int row = blockIdx.x;
    int t = threadIdx.x;
    const float4* p = (const float4*)(in + (size_t)row * D);
    float4 v = p[t];                       // 256 threads * 4 = 1024
    float ss = v.x * v.x + v.y * v.y + v.z * v.z + v.w * v.w;
    int lane = t & 63, wid = t >> 6;
    #pragma unroll
    for (int off = 1; off < 64; off <<= 1) ss += __shfl_xor(ss, off);
    __shared__ float sred[4];
    if (lane == 0) sred[wid] = ss;
    __syncthreads();
    float tot = sred[0] + sred[1] + sred[2] + sred[3];
    float inv = 1.0f / sqrtf(tot);
    if (t == 0) inv_norm[row] = inv;
    ushort4 o;
    __hip_bfloat16 h;
    h = __float2bfloat16(v.x * inv); o.x = *(ushort*)&h;
    h = __float2bfloat16(v.y * inv); o.y = *(ushort*)&h;
    h = __float2bfloat16(v.z * inv); o.z = *(ushort*)&h;
    h = __float2bfloat16(v.w * inv); o.w = *(ushort*)&h;
    ((ushort4*)(xn + (size_t)row * D))[t] = o;
}

// ---------------- K2: exact fp32 positive sims per group (8x8 Gram) ----------------
// 256 threads: 64 pairs x 4 D-slices, shfl-reduce across slices.
__global__ __launch_bounds__(256) void k_pos(const float* __restrict__ in,
                                             const float* __restrict__ inv_norm,
                                             float* __restrict__ pos_sims,
                                             float* __restrict__ min_pos) {
    int g = blockIdx.x;
    int t = threadIdx.x;
    int pair = t >> 2;          // 0..63
    int a = pair >> 3, b = pair & 7;
    int slice = t & 3;
    int ra = g * 8 + a, rb = g * 8 + b;
    const float4* pa = (const float4*)(in + (size_t)ra * D) + slice * 64;
    const float4* pb = (const float4*)(in + (size_t)rb * D) + slice * 64;
    float s = 0.f;
    #pragma unroll 8
    for (int i = 0; i < 64; ++i) {
        float4 x = pa[i], y = pb[i];
        s += x.x * y.x + x.y * y.y + x.z * y.z + x.w * y.w;
    }
    s += __shfl_xor(s, 1);
    s += __shfl_xor(s, 2);
    float sim = s * inv_norm[ra] * inv_norm[rb];
    __shared__ float sg[8][8];
    if (slice == 0) sg[a][b] = sim;
    __syncthreads();
    if (t < 8) {
        float mn = 1e30f;
        int idx = 0;
        #pragma unroll
        for (int b2 = 0; b2 < 8; ++b2) {
            if (b2 == t) continue;
            float v = sg[t][b2];
            mn = fminf(mn, v);
            pos_sims[(size_t)(g * 8 + t) * 8 + idx] = v;
            ++idx;
        }
        min_pos[g * 8 + t] = mn;
    }
}

// ---------------- K3: bf16 MFMA sim tiles (LDS-staged) + fused negative reductions ----------------
// grid (32, 32); block 256 = 4 waves in 2x2; 128x128 tile per block; BK=32.
__global__ __launch_bounds__(256) void k_neg(const ushort* __restrict__ xn,
                                             const float* __restrict__ min_pos,
                                             float* __restrict__ sum_part,
                                             int* __restrict__ cnt_part,
                                             float* __restrict__ max_part,
                                             unsigned* __restrict__ gmax) {
    __shared__ ushort sA[128 * 32];   // [row][k] row-major
    __shared__ ushort sB[128 * 32];
    __shared__ float sMin[128];

    int rt = blockIdx.y, ct = blockIdx.x;
    int R0 = rt * 128, C0 = ct * 128;
    int t = threadIdx.x, lane = t & 63, wid = t >> 6;
    int wr = wid >> 1, wc = wid & 1;

    if (t < 128) sMin[t] = min_pos[R0 + t];

    // staging addresses: thread t loads 8 bf16 (16B): row = t>>2 (+64 for issue 1),
    // k-offset = (t&3)*8. Linear LDS byte offset = issue*4096 + t*16.
    int srow = t >> 2;
    int skoff = (t & 3) * 8;
    const ushort* gA0 = xn + (size_t)(R0 + srow) * D + skoff;
    const ushort* gA1 = xn + (size_t)(R0 + 64 + srow) * D + skoff;
    const ushort* gB0 = xn + (size_t)(C0 + srow) * D + skoff;
    const ushort* gB1 = xn + (size_t)(C0 + 64 + srow) * D + skoff;
    char* lA = (char*)sA;
    char* lB = (char*)sB;
    unsigned wbase = (unsigned)wid * 1024;   // 64 lanes * 16B per wave

    int lrow = lane & 15;
    int kgrp = lane >> 4;    // 0..3 -> k-octet

    f32x4 zero = {0.f, 0.f, 0.f, 0.f};
    f32x4 acc[4][4];
    #pragma unroll
    for (int m = 0; m < 4; ++m)
        #pragma unroll
        for (int n = 0; n < 4; ++n) acc[m][n] = zero;

    // LDS fragment byte addresses (constant across k-loop)
    const ushort* fA = sA + (size_t)(wr * 64 + lrow) * 32 + kgrp * 8;
    const ushort* fB = sB + (size_t)(wc * 64 + lrow) * 32 + kgrp * 8;

    for (int k0 = 0; k0 < D; k0 += 32) {
        __syncthreads();   // previous tile's reads complete before overwrite
        gld16(gA0 + k0, lA + wbase);
        gld16(gA1 + k0, lA + 4096 + wbase);
        gld16(gB0 + k0, lB + wbase);
        gld16(gB1 + k0, lB + 4096 + wbase);
        __syncthreads();   // compiler emits vmcnt(0) drain before barrier

        bf16x8 a[4], b[4];
        #pragma unroll
        for (int m = 0; m < 4; ++m)
            a[m] = *(const bf16x8*)(fA + (size_t)m * 16 * 32);
        #pragma unroll
        for (int n = 0; n < 4; ++n)
            b[n] = *(const bf16x8*)(fB + (size_t)n * 16 * 32);
        #pragma unroll
        for (int m = 0; m < 4; ++m)
            #pragma unroll
            for (int n = 0; n < 4; ++n)
                acc[m][n] = __builtin_amdgcn_mfma_f32_16x16x32_bf16(a[m], b[n], acc[m][n], 0, 0, 0);
    }

    // epilogue: per-row negative stats + global max
    float allmax = -1e30f;
    int pc = ct * 2 + wc;
    int cbase = C0 + wc * 64;
    #pragma unroll
    for (int m = 0; m < 4; ++m) {
        #pragma unroll
        for (int reg = 0; reg < 4; ++reg) {
            int lr = wr * 64 + m * 16 + kgrp * 4 + reg;   // local row in [0,128)
            int grow = R0 + lr;
            float th = sMin[lr] - 0.05f;
            int gi = grow >> 3;
            float rs = 0.f, rm = -1e30f;
            int rc = 0;
            #pragma unroll
            for (int n = 0; n < 4; ++n) {
                int gcol = cbase + n * 16 + lrow;
                float s = acc[m][n][reg];
                allmax = fmaxf(allmax, s);
                if ((gcol >> 3) != gi) {
                    rm = fmaxf(rm, s);
                    if (s > th) { rs += softplus(ALPHA * (s - MARGIN)); rc += 1; }
                }
            }
            // reduce across the 16 col-lanes (same kgrp group)
            #pragma unroll
            for (int off = 1; off < 16; off <<= 1) {
                rs += __shfl_xor(rs, off);
                rc += __shfl_xor(rc, off);
                rm = fmaxf(rm, __shfl_xor(rm, off));
            }
            if (lrow == 0) {
                sum_part[(size_t)pc * N + grow] = rs;
                cnt_part[(size_t)pc * N + grow] = rc;
                max_part[(size_t)pc * N + grow] = rm;
            }
        }
    }
    #pragma unroll
    for (int off = 1; off < 64; off <<= 1) allmax = fmaxf(allmax, __shfl_xor(allmax, off));
    if (lane == 0) atomicMax(gmax, fkey(allmax));
}

// ---------------- K4a: per-row combine ----------------
__global__ __launch_bounds__(256) void k_row(const float* __restrict__ sum_part,
                                             const int* __restrict__ cnt_part,
                                             const float* __restrict__ max_part,
                                             const float* __restrict__ pos_sims,
                                             const float* __restrict__ min_pos,
                                             const unsigned* __restrict__ gmax,
                                             float* __restrict__ row_loss) {
    int row = blockIdx.x * 256 + threadIdx.x;
    if (row >= N) return;
    float base = fmaxf(fdec(*gmax) - 0.1f, MARGIN + 0.2f);
    float ns = 0.f, nm = -1e30f;
    int nc = 0;
    for (int p = 0; p < 64; ++p) {
        ns += sum_part[(size_t)p * N + row];
        nc += cnt_part[(size_t)p * N + row];
        nm = fmaxf(nm, max_part[(size_t)p * N + row]);
    }
    float neg_loss = (nc > 0) ? ns / (float)nc : softplus(ALPHA * (nm - MARGIN));
    float ps = 0.f;
    int pcnt = 0;
    float mn = min_pos[row];
    #pragma unroll
    for (int i = 0; i < NINST - 1; ++i) {
        float s = pos_sims[(size_t)row * 8 + i];
        if (s < base) { ps += softplus(-2.0f * (s - MARGIN)); pcnt++; }
    }
    float pos_loss = (pcnt > 0) ? ps / (float)pcnt : softplus(-2.0f * (mn - MARGIN));
    row_loss[row] = pos_loss + neg_loss;
}

// ---------------- K4b: deterministic mean ----------------
__global__ __launch_bounds__(256) void k_final(const float* __restrict__ row_loss,
                                               float* __restrict__ out) {
    __shared__ float sred[256];
    int t = threadIdx.x;
    float s = 0.f;
    for (int i = t; i < N; i += 256) s += row_loss[i];
    sred[t] = s;
    __syncthreads();
    for (int off = 128; off; off >>= 1) {
        if (t < off) sred[t] += sred[t + off];
        __syncthreads();
    }
    if (t == 0) out[0] = sred[0] / (float)N;
}

extern "C" void kernel_launch(void* const* d_in, const int* in_sizes, int n_in,
                              void* d_out, int out_size, void* d_ws, size_t ws_size,
                              hipStream_t stream) {
    const float* in = (const float*)d_in[0];
    float* out = (float*)d_out;

    char* ws = (char*)d_ws;
    ushort*  xn       = (ushort*)(ws);                          // 8 MB
    float*   inv_norm = (float*)(ws + 8388608);                 // 16 KB
    float*   min_pos  = (float*)(ws + 8388608 + 16384);         // 16 KB
    float*   pos_sims = (float*)(ws + 8388608 + 32768);         // 128 KB
    float*   sum_part = (float*)(ws + 8388608 + 32768 + 131072);            // 1 MB
    float*   max_part = (float*)(ws + 8388608 + 32768 + 131072 + 1048576);  // 1 MB
    int*     cnt_part = (int*)  (ws + 8388608 + 32768 + 131072 + 2097152);  // 1 MB
    float*   row_loss = (float*)(ws + 8388608 + 32768 + 131072 + 3145728);  // 16 KB
    unsigned* gmax    = (unsigned*)(ws + 8388608 + 32768 + 131072 + 3145728 + 16384);

    hipMemsetAsync(gmax, 0, sizeof(unsigned), stream);

    k_norm<<<N, 256, 0, stream>>>(in, xn, inv_norm);
    k_pos<<<NGROUP, 256, 0, stream>>>(in, inv_norm, pos_sims, min_pos);
    k_neg<<<dim3(32, 32), 256, 0, stream>>>(xn, min_pos, sum_part, cnt_part, max_part, gmax);
    k_row<<<N / 256, 256, 0, stream>>>(sum_part, cnt_part, max_part, pos_sims, min_pos, gmax, row_loss);
    k_final<<<1, 256, 0, stream>>>(row_loss, out);
}